// Round 10
// baseline (2010.853 us; speedup 1.0000x reference)
//
#include <hip/hip_runtime.h>
#include <hip/hip_bf16.h>
#include <math.h>

#define BB   2048
#define LL   60
#define DD   80
#define HH   8
#define HDD  10
#define NLNUM 3
#define NLOC 1187
#define DFF  160
#define IN_DIM 138
#define RELN 119
#define SCS  68   // scT row stride (floats)
#define XP   21   // padded tile row stride in float4 (84 words)
#define HP   41   // padded h-tile row stride in float4
#define VP   35   // vin row stride in float4

// Branchless gelu: erf via Abramowitz-Stegun 7.1.26 (|err| <= 1.5e-7).
__device__ __forceinline__ float gelu_f(float a) {
  float x = fabsf(a) * 0.70710678118654752f;
  float t = 1.0f / (1.0f + 0.3275911f * x);
  float y = t * (0.254829592f + t * (-0.284496736f + t * (1.421413741f +
            t * (-1.453152027f + t * 1.061405429f))));
  float e = 1.0f - y * __expf(-x * x);
  float erf_s = copysignf(e, a);
  return 0.5f * a * (1.0f + erf_s);
}

// ---------------------------------------------------------------------------
// K0: transpose qkv_w into [l][h][i:80][c:32] (c = q0-9,k0-9,v0-9, pad 30-31)
// i-major with c contiguous so GEMM lane-fast reads are conflict-free.
// ---------------------------------------------------------------------------
__global__ __launch_bounds__(256) void k_wprep(
    const float* __restrict__ qkv_w, float* __restrict__ wT) {
  int idx = blockIdx.x * 256 + threadIdx.x;     // 3*8*80*32 = 61440
  if (idx >= 61440) return;
  int c = idx & 31;
  int i = (idx >> 5) % 80;
  int h = ((idx >> 5) / 80) % 8;
  int l = idx / (32 * 80 * 8);
  float v = 0.0f;
  if (c < 30) {
    int col = (c < 10) ? (h * 10 + c)
            : (c < 20) ? (80 + h * 10 + (c - 10))
                       : (160 + h * 10 + (c - 20));
    v = qkv_w[(size_t)l * 19200 + (size_t)i * 240 + col];
  }
  wT[idx] = v;
}

// ---------------------------------------------------------------------------
// K1: embed+inproj+LN as a 48-token GEMM block
// ---------------------------------------------------------------------------
__global__ __launch_bounds__(256) void k_embed(
    const int* __restrict__ loc_seq, const int* __restrict__ user_seq,
    const int* __restrict__ wk_seq, const int* __restrict__ sm_seq,
    const int* __restrict__ dur_seq, const int* __restrict__ diff_seq,
    const float* __restrict__ loc_table, const float* __restrict__ user_table,
    const float* __restrict__ wk_table, const float* __restrict__ hr_table,
    const float* __restrict__ in_w, const float* __restrict__ in_b,
    const float* __restrict__ in_g, const float* __restrict__ in_be,
    const float* __restrict__ pos_emb, float* __restrict__ x) {
  int tok0 = blockIdx.x * 48, tid = threadIdx.x;
  __shared__ __align__(16) float vin[48 * VP * 4];
  __shared__ __align__(16) float ws[140 * 80];
  __shared__ float mstd[96];

  float4* vin4 = (float4*)vin;
  float4* ws4  = (float4*)ws;

  for (int i = tid; i < 140 * 20; i += 256) {
    int r = i / 20, c = i % 20;
    float4 v = make_float4(0.0f, 0.0f, 0.0f, 0.0f);
    if (r < IN_DIM) v = *(const float4*)(in_w + r * 80 + c * 4);
    ws4[i] = v;
  }
  for (int i = tid; i < 48 * 35; i += 256) {
    int t = i / 35, s = i % 35;
    int tok = tok0 + t;
    float4 v;
    if (s < 20) {
      int loc = loc_seq[tok];
      v = *(const float4*)(loc_table + (size_t)loc * 80 + s * 4);
    } else if (s < 26) {
      int usr = user_seq[(tok / LL) * LL];
      v = *(const float4*)(user_table + usr * 24 + (s - 20) * 4);
    } else if (s < 30) {
      int wk = wk_seq[tok];
      v = *(const float4*)(wk_table + wk * 16 + (s - 26) * 4);
    } else if (s < 34) {
      int hr = sm_seq[tok] / 60; hr = min(max(hr, 0), 23);
      v = *(const float4*)(hr_table + hr * 16 + (s - 30) * 4);
    } else {
      v.x = (float)diff_seq[tok] / 10.0f;
      v.y = (float)dur_seq[tok] / 300.0f;
      v.z = 0.0f; v.w = 0.0f;
    }
    vin4[t * VP + s] = v;
  }
  __syncthreads();

  int tg = tid / 20, cg = tid % 20, t0 = tg * 4;
  float acc[4][4] = {};
  if (tid < 240) {
    #pragma unroll 7
    for (int iq = 0; iq < 35; iq++) {
      float4 xv[4], wv[4];
      #pragma unroll
      for (int dt = 0; dt < 4; dt++) xv[dt] = vin4[(t0 + dt) * VP + iq];
      #pragma unroll
      for (int di = 0; di < 4; di++) wv[di] = ws4[(iq * 4 + di) * 20 + cg];
      #pragma unroll
      for (int dt = 0; dt < 4; dt++) {
        const float* xp = (const float*)&xv[dt];
        #pragma unroll
        for (int di = 0; di < 4; di++) {
          const float* wp = (const float*)&wv[di];
          #pragma unroll
          for (int dc = 0; dc < 4; dc++) acc[dt][dc] += xp[di] * wp[dc];
        }
      }
    }
  }
  __syncthreads();
  if (tid < 240) {
    float4 bb = *(const float4*)(in_b + cg * 4);
    const float* bp = (const float*)&bb;
    #pragma unroll
    for (int dt = 0; dt < 4; dt++) {
      float4 y;
      y.x = acc[dt][0] + bp[0];
      y.y = acc[dt][1] + bp[1];
      y.z = acc[dt][2] + bp[2];
      y.w = acc[dt][3] + bp[3];
      vin4[(t0 + dt) * VP + cg] = y;
    }
  }
  __syncthreads();
  if (tid < 48) {
    float s = 0.0f, s2 = 0.0f;
    #pragma unroll
    for (int iq = 0; iq < 20; iq++) {
      float4 v = vin4[tid * VP + iq];
      s  += v.x + v.y + v.z + v.w;
      s2 += v.x * v.x + v.y * v.y + v.z * v.z + v.w * v.w;
    }
    float mean = s / 80.0f;
    float var  = fmaxf(s2 / 80.0f - mean * mean, 0.0f);
    mstd[tid] = mean; mstd[48 + tid] = rsqrtf(var + 1e-5f);
  }
  __syncthreads();
  for (int e = tid; e < 960; e += 256) {
    int t = e / 20, c4 = e % 20;
    float4 v = vin4[t * VP + c4];
    float4 gg = *(const float4*)(in_g + c4 * 4);
    float4 bb = *(const float4*)(in_be + c4 * 4);
    float4 pe = *(const float4*)(pos_emb + ((tok0 + t) % LL) * 80 + c4 * 4);
    float m = mstd[t], r = mstd[48 + t];
    float4 out;
    out.x = (v.x - m) * r * gg.x + bb.x + pe.x;
    out.y = (v.y - m) * r * gg.y + bb.y + pe.y;
    out.z = (v.z - m) * r * gg.z + bb.z + pe.z;
    out.w = (v.w - m) * r * gg.w + bb.w + pe.w;
    ((float4*)(x + (size_t)tok0 * 80))[e] = out;
  }
}

// ---------------------------------------------------------------------------
// K2: fused qkv + attention v3 — conflict-clean mappings.
// All LDS phases: lane-fast index walks the contiguous dimension.
// scT stores scores TRANSPOSED [j][i]; softmax is per-column.
// ---------------------------------------------------------------------------
__global__ __launch_bounds__(256) void k_battn(
    const float* __restrict__ x, const int* __restrict__ loc_seq,
    const float* __restrict__ wT,       // layer slice [8][80][32]
    const float* __restrict__ rel_emb,  // layer slice [119][10]
    float* __restrict__ o) {
  int b = blockIdx.x, tid = threadIdx.x;

  __shared__ __align__(16) float xs[LL * XP * 4];    // 20160 B
  __shared__ __align__(16) float qkvh[32 * 60];      // 7680 B (rows 30/31 pad)
  __shared__ __align__(16) float scbuf[LL * SCS];    // 16320 B: scT | w-stage
  __shared__ __align__(16) float relT[HDD * 120];    // 4800 B
  __shared__ __align__(16) float rsum[64];
  __shared__ float msk[60];

  float4* xs4  = (float4*)xs;
  float4* wst4 = (float4*)scbuf;      // [i:80][c4:8] = 640 f4
  float* scT   = scbuf;               // [j:60][stride SCS]

  const float4* xb4 = (const float4*)(x + (size_t)b * 4800);
  for (int i = tid; i < 1200; i += 256) xs4[(i / 20) * XP + (i % 20)] = xb4[i];
  for (int i = tid; i < RELN * HDD; i += 256) {
    int d = i / RELN, p = i % RELN;
    relT[d * 120 + p] = rel_emb[p * 10 + d];
  }
  if (tid < 60) msk[tid] = (loc_seq[b * LL + tid] == 0) ? 1.0f : 0.0f;

  for (int h = 0; h < HH; h++) {
    __syncthreads();   // prior head's scT reads (AV) done -> w overlay safe
    const float4* w4 = (const float4*)(wT + (size_t)h * 2560);
    for (int i = tid; i < 640; i += 256) wst4[i] = w4[i];
    __syncthreads();   // w staged

    // qkv GEMM: 120 threads, 4c x 4t tiles; cg fast reads contiguous w f4s.
    if (tid < 120) {
      int cg = tid & 7, tg = tid >> 3;
      int c0 = cg * 4, t0 = tg * 4;
      float acc[4][4] = {};   // [dc][dt]
      #pragma unroll 5
      for (int iq = 0; iq < 20; iq++) {
        float4 xv[4], wv[4];
        #pragma unroll
        for (int dt = 0; dt < 4; dt++) xv[dt] = xs4[(t0 + dt) * XP + iq];
        #pragma unroll
        for (int di = 0; di < 4; di++) wv[di] = wst4[(iq * 4 + di) * 8 + cg];
        #pragma unroll
        for (int di = 0; di < 4; di++) {
          const float* wp = (const float*)&wv[di];
          #pragma unroll
          for (int dt = 0; dt < 4; dt++) {
            const float* xp = (const float*)&xv[dt];
            #pragma unroll
            for (int dc = 0; dc < 4; dc++)
              acc[dc][dt] += wp[dc] * xp[di];
          }
        }
      }
      #pragma unroll
      for (int dc = 0; dc < 4; dc++)
        *(float4*)(qkvh + (c0 + dc) * 60 + t0) =
            make_float4(acc[dc][0], acc[dc][1], acc[dc][2], acc[dc][3]);
    }
    __syncthreads();   // qkvh ready; w reads done -> scT writable

    // scores -> scT[j][i]; ig fast (stride-4 reads/writes, 2-way max)
    if (tid < 225) {
      int ig = tid % 15, jg = tid / 15;
      int i0 = ig * 4, j0 = jg * 4;
      int w0 = j0 - i0 + 56;
      float acc[4][4] = {};   // [di][dj]
      #pragma unroll
      for (int d = 0; d < 10; d++) {
        float4 qv = *(const float4*)(qkvh + d * 60 + i0);
        float4 kv = *(const float4*)(qkvh + 600 + d * 60 + j0);
        float4 rA = *(const float4*)(relT + d * 120 + w0);
        float4 rB = *(const float4*)(relT + d * 120 + w0 + 4);
        float rr[8] = {rA.x, rA.y, rA.z, rA.w, rB.x, rB.y, rB.z, rB.w};
        const float* qp = (const float*)&qv;
        const float* kp = (const float*)&kv;
        #pragma unroll
        for (int di = 0; di < 4; di++)
          #pragma unroll
          for (int dj = 0; dj < 4; dj++)
            acc[di][dj] += qp[di] * (kp[dj] + rr[dj - di + 3]);
      }
      const float scale = 0.31622776601683794f;
      #pragma unroll
      for (int dj = 0; dj < 4; dj++) {
        float mk = msk[j0 + dj];
        float4 col;
        col.x = (mk != 0.0f) ? -1e30f : acc[0][dj] * scale;
        col.y = (mk != 0.0f) ? -1e30f : acc[1][dj] * scale;
        col.z = (mk != 0.0f) ? -1e30f : acc[2][dj] * scale;
        col.w = (mk != 0.0f) ? -1e30f : acc[3][dj] * scale;
        *(float4*)(scT + (j0 + dj) * SCS + i0) = col;
      }
    }
    __syncthreads();   // scT scores ready

    // softmax over j (rows of scT) for each column i: thread i scans column.
    // Per-instruction lanes vary i (stride 1 word) -> conflict-free.
    if (tid < 60) {
      float m = -3.0e38f;
      #pragma unroll 10
      for (int j = 0; j < 60; j++) m = fmaxf(m, scT[j * SCS + tid]);
      float sum = 0.0f;
      #pragma unroll 10
      for (int j = 0; j < 60; j++) {
        float e = __expf(scT[j * SCS + tid] - m);
        scT[j * SCS + tid] = e;
        sum += e;
      }
      rsum[tid] = 1.0f / sum;
    }
    __syncthreads();   // softmaxed scT + rsum ready

    // AV: O[i][d] = sum_j scT[j][i] * v[d][j]; ig fast, d slow.
    if (tid < 150) {
      int ig = tid % 15, d = tid / 15;
      int i0 = 4 * ig;
      const float* vsr = qkvh + 1200 + d * 60;
      float acc[4] = {0, 0, 0, 0};
      #pragma unroll 5
      for (int jq = 0; jq < 15; jq++) {
        float4 vv = *(const float4*)(vsr + jq * 4);
        const float* vp = (const float*)&vv;
        #pragma unroll
        for (int dj = 0; dj < 4; dj++) {
          float4 scv = *(const float4*)(scT + (4 * jq + dj) * SCS + i0);
          const float* sp = (const float*)&scv;
          #pragma unroll
          for (int di = 0; di < 4; di++) acc[di] += sp[di] * vp[dj];
        }
      }
      #pragma unroll
      for (int di = 0; di < 4; di++) {
        int t = i0 + di;
        o[((size_t)b * 60 + t) * 80 + h * 10 + d] = acc[di] * rsum[t];
      }
    }
  }
}

// ---------------------------------------------------------------------------
// K3: x = LN(x + o @ proj_w + proj_b)  — 48 tokens/block
// ---------------------------------------------------------------------------
__global__ __launch_bounds__(256) void k_proj_ln(
    const float* __restrict__ o, const float* __restrict__ proj_w,
    const float* __restrict__ proj_b, const float* __restrict__ g,
    const float* __restrict__ be, float* __restrict__ x) {
  int tok0 = blockIdx.x * 48, tid = threadIdx.x;
  __shared__ __align__(16) float os[48 * XP * 4];
  __shared__ __align__(16) float ws[80 * 80];
  __shared__ float mstd[96];

  float4* os4 = (float4*)os;
  const float4* ob4 = (const float4*)(o + (size_t)tok0 * 80);
  for (int i = tid; i < 960; i += 256) os4[(i / 20) * XP + (i % 20)] = ob4[i];
  float4* ws4 = (float4*)ws;
  for (int i = tid; i < 1600; i += 256)
    ws4[i] = *(const float4*)(proj_w + (i / 20) * 80 + (i % 20) * 4);
  __syncthreads();

  int tg = tid / 20, cg = tid % 20, t0 = tg * 4;
  float acc[4][4] = {};
  if (tid < 240) {
    #pragma unroll
    for (int iq = 0; iq < 20; iq++) {
      float4 xv[4], wv[4];
      #pragma unroll
      for (int dt = 0; dt < 4; dt++) xv[dt] = os4[(t0 + dt) * XP + iq];
      #pragma unroll
      for (int di = 0; di < 4; di++) wv[di] = ws4[(iq * 4 + di) * 20 + cg];
      #pragma unroll
      for (int dt = 0; dt < 4; dt++) {
        const float* xp = (const float*)&xv[dt];
        #pragma unroll
        for (int di = 0; di < 4; di++) {
          const float* wp = (const float*)&wv[di];
          #pragma unroll
          for (int dc = 0; dc < 4; dc++) acc[dt][dc] += xp[di] * wp[dc];
        }
      }
    }
  }
  __syncthreads();
  if (tid < 240) {
    float4 pb = *(const float4*)(proj_b + cg * 4);
    const float* pbp = (const float*)&pb;
    #pragma unroll
    for (int dt = 0; dt < 4; dt++) {
      float4 xr = *(const float4*)(x + (size_t)(tok0 + t0 + dt) * 80 + cg * 4);
      const float* xrp = (const float*)&xr;
      float4 out;
      out.x = acc[dt][0] + pbp[0] + xrp[0];
      out.y = acc[dt][1] + pbp[1] + xrp[1];
      out.z = acc[dt][2] + pbp[2] + xrp[2];
      out.w = acc[dt][3] + pbp[3] + xrp[3];
      os4[(t0 + dt) * XP + cg] = out;
    }
  }
  __syncthreads();
  if (tid < 48) {
    float s = 0.0f, s2 = 0.0f;
    #pragma unroll
    for (int iq = 0; iq < 20; iq++) {
      float4 v = os4[tid * XP + iq];
      s  += v.x + v.y + v.z + v.w;
      s2 += v.x * v.x + v.y * v.y + v.z * v.z + v.w * v.w;
    }
    float mean = s / 80.0f;
    float var  = fmaxf(s2 / 80.0f - mean * mean, 0.0f);
    mstd[tid] = mean; mstd[48 + tid] = rsqrtf(var + 1e-5f);
  }
  __syncthreads();
  for (int e = tid; e < 960; e += 256) {
    int t = e / 20, c4 = e % 20;
    float4 v = os4[t * XP + c4];
    float4 gg = *(const float4*)(g + c4 * 4);
    float4 bb = *(const float4*)(be + c4 * 4);
    float m = mstd[t], r = mstd[48 + t];
    float4 out;
    out.x = (v.x - m) * r * gg.x + bb.x;
    out.y = (v.y - m) * r * gg.y + bb.y;
    out.z = (v.z - m) * r * gg.z + bb.z;
    out.w = (v.w - m) * r * gg.w + bb.w;
    ((float4*)(x + (size_t)tok0 * 80))[e] = out;
  }
}

// ---------------------------------------------------------------------------
// K4: fused FFN: x = LN(x + W2ᵀgelu(W1ᵀx + b1) + b2)  — 48 tokens/block
// ---------------------------------------------------------------------------
__global__ __launch_bounds__(256) void k_ffn(
    const float* __restrict__ w1, const float* __restrict__ b1,
    const float* __restrict__ w2, const float* __restrict__ b2,
    const float* __restrict__ g, const float* __restrict__ be,
    float* __restrict__ x) {
  int tok0 = blockIdx.x * 48, tid = threadIdx.x;
  __shared__ __align__(16) float xs[48 * XP * 4];
  __shared__ __align__(16) float hs[48 * HP * 4];
  __shared__ __align__(16) float ws[80 * 80];
  __shared__ float mstd[96];

  float4* xs4 = (float4*)xs;
  float4* hs4 = (float4*)hs;
  float4* ws4 = (float4*)ws;
  const float4* xb4 = (const float4*)(x + (size_t)tok0 * 80);
  for (int i = tid; i < 960; i += 256) xs4[(i / 20) * XP + (i % 20)] = xb4[i];

  int tg = tid / 20, cg = tid % 20, t0 = tg * 4;

  for (int c0 = 0; c0 < 160; c0 += 80) {
    __syncthreads();
    for (int i = tid; i < 1600; i += 256)
      ws4[i] = *(const float4*)(w1 + (i / 20) * 160 + c0 + (i % 20) * 4);
    __syncthreads();
    if (tid < 240) {
      float acc[4][4] = {};
      #pragma unroll
      for (int iq = 0; iq < 20; iq++) {
        float4 xv[4], wv[4];
        #pragma unroll
        for (int dt = 0; dt < 4; dt++) xv[dt] = xs4[(t0 + dt) * XP + iq];
        #pragma unroll
        for (int di = 0; di < 4; di++) wv[di] = ws4[(iq * 4 + di) * 20 + cg];
        #pragma unroll
        for (int dt = 0; dt < 4; dt++) {
          const float* xp = (const float*)&xv[dt];
          #pragma unroll
          for (int di = 0; di < 4; di++) {
            const float* wp = (const float*)&wv[di];
            #pragma unroll
            for (int dc = 0; dc < 4; dc++) acc[dt][dc] += xp[di] * wp[dc];
          }
        }
      }
      float4 bb = *(const float4*)(b1 + c0 + cg * 4);
      const float* bp = (const float*)&bb;
      #pragma unroll
      for (int dt = 0; dt < 4; dt++) {
        float4 out;
        float* op = (float*)&out;
        #pragma unroll
        for (int dc = 0; dc < 4; dc++)
          op[dc] = gelu_f(acc[dt][dc] + bp[dc]);
        hs4[(t0 + dt) * HP + c0 / 4 + cg] = out;
      }
    }
  }

  float acc[4][4] = {};
  for (int k0 = 0; k0 < 160; k0 += 80) {
    __syncthreads();
    for (int i = tid; i < 1600; i += 256)
      ws4[i] = *(const float4*)(w2 + (size_t)(k0 + i / 20) * 80 + (i % 20) * 4);
    __syncthreads();
    if (tid < 240) {
      #pragma unroll
      for (int iq = 0; iq < 20; iq++) {
        float4 hv[4], wv[4];
        #pragma unroll
        for (int dt = 0; dt < 4; dt++) hv[dt] = hs4[(t0 + dt) * HP + k0 / 4 + iq];
        #pragma unroll
        for (int di = 0; di < 4; di++) wv[di] = ws4[(iq * 4 + di) * 20 + cg];
        #pragma unroll
        for (int dt = 0; dt < 4; dt++) {
          const float* hp = (const float*)&hv[dt];
          #pragma unroll
          for (int di = 0; di < 4; di++) {
            const float* wp = (const float*)&wv[di];
            #pragma unroll
            for (int dc = 0; dc < 4; dc++) acc[dt][dc] += hp[di] * wp[dc];
          }
        }
      }
    }
  }
  __syncthreads();
  if (tid < 240) {
    float4 bb = *(const float4*)(b2 + cg * 4);
    const float* bp = (const float*)&bb;
    #pragma unroll
    for (int dt = 0; dt < 4; dt++) {
      float4 xr = xs4[(t0 + dt) * XP + cg];
      const float* xrp = (const float*)&xr;
      float4 out;
      out.x = acc[dt][0] + bp[0] + xrp[0];
      out.y = acc[dt][1] + bp[1] + xrp[1];
      out.z = acc[dt][2] + bp[2] + xrp[2];
      out.w = acc[dt][3] + bp[3] + xrp[3];
      hs4[(t0 + dt) * HP + cg] = out;
    }
  }
  __syncthreads();
  if (tid < 48) {
    float s = 0.0f, s2 = 0.0f;
    #pragma unroll
    for (int iq = 0; iq < 20; iq++) {
      float4 v = hs4[tid * HP + iq];
      s  += v.x + v.y + v.z + v.w;
      s2 += v.x * v.x + v.y * v.y + v.z * v.z + v.w * v.w;
    }
    float mean = s / 80.0f;
    float var  = fmaxf(s2 / 80.0f - mean * mean, 0.0f);
    mstd[tid] = mean; mstd[48 + tid] = rsqrtf(var + 1e-5f);
  }
  __syncthreads();
  for (int e = tid; e < 960; e += 256) {
    int t = e / 20, c4 = e % 20;
    float4 v = hs4[t * HP + c4];
    float4 gg = *(const float4*)(g + c4 * 4);
    float4 bb = *(const float4*)(be + c4 * 4);
    float m = mstd[t], r = mstd[48 + t];
    float4 out;
    out.x = (v.x - m) * r * gg.x + bb.x;
    out.y = (v.y - m) * r * gg.y + bb.y;
    out.z = (v.z - m) * r * gg.z + bb.z;
    out.w = (v.w - m) * r * gg.w + bb.w;
    ((float4*)(x + (size_t)tok0 * 80))[e] = out;
  }
}

// ---------------------------------------------------------------------------
// K5: final LN at gathered position + fnorm + h1 = gelu(final@pr_w1+pr_b1)
// ---------------------------------------------------------------------------
__global__ __launch_bounds__(128) void k_final(
    const float* __restrict__ x, const int* __restrict__ seq_len,
    const float* __restrict__ fn_g, const float* __restrict__ fn_b,
    const float* __restrict__ pr_w1, const float* __restrict__ pr_b1,
    float* __restrict__ fnorm, float* __restrict__ h1) {
  int b = blockIdx.x, tid = threadIdx.x;
  __shared__ float red[128], red2[128];
  __shared__ float fbuf[DD];
  int t = seq_len[b] - 1; t = min(max(t, 0), LL - 1);
  float v = 0.0f;
  if (tid < DD) v = x[((size_t)b * LL + t) * DD + tid];
  red[tid]  = (tid < DD) ? v : 0.0f;
  red2[tid] = (tid < DD) ? v * v : 0.0f;
  __syncthreads();
  for (int s = 64; s > 0; s >>= 1) {
    if (tid < s) { red[tid] += red[tid + s]; red2[tid] += red2[tid + s]; }
    __syncthreads();
  }
  float mean = red[0] / DD;
  float var  = fmaxf(red2[0] / DD - mean * mean, 0.0f);
  float rstd = rsqrtf(var + 1e-5f);
  float f = 0.0f;
  if (tid < DD) { f = (v - mean) * rstd * fn_g[tid] + fn_b[tid]; fbuf[tid] = f; }
  __syncthreads();
  red[tid] = (tid < DD) ? f * f : 0.0f;
  __syncthreads();
  for (int s = 64; s > 0; s >>= 1) {
    if (tid < s) red[tid] += red[tid + s];
    __syncthreads();
  }
  float rn = 1.0f / fmaxf(sqrtf(red[0]), 1e-12f);
  if (tid < DD) {
    fnorm[(size_t)b * DD + tid] = f * rn;
    float gacc = pr_b1[tid];
    for (int i = 0; i < DD; i++) gacc += fbuf[i] * pr_w1[i * DD + tid];
    h1[(size_t)b * DD + tid] = gelu_f(gacc);
  }
}

// ---------------------------------------------------------------------------
// K6: normalize proto rows -> transposed pnormT[k][c]
// ---------------------------------------------------------------------------
__global__ __launch_bounds__(128) void k_pnorm(
    const float* __restrict__ protos, float* __restrict__ pnormT) {
  int c = blockIdx.x, tid = threadIdx.x;
  __shared__ float red[128];
  float v = 0.0f;
  if (tid < DD) v = protos[(size_t)c * DD + tid];
  red[tid] = (tid < DD) ? v * v : 0.0f;
  __syncthreads();
  for (int s = 64; s > 0; s >>= 1) {
    if (tid < s) red[tid] += red[tid + s];
    __syncthreads();
  }
  float rn = 1.0f / fmaxf(sqrtf(red[0]), 1e-12f);
  if (tid < DD) pnormT[(size_t)tid * NLOC + c] = v * rn;
}

// ---------------------------------------------------------------------------
// K7: logits
// ---------------------------------------------------------------------------
__global__ __launch_bounds__(256) void k_logits(
    const float* __restrict__ h1, const float* __restrict__ fnorm,
    const float* __restrict__ pr_w2, const float* __restrict__ pr_b2,
    const float* __restrict__ pnormT, const float* __restrict__ temp,
    float* __restrict__ out) {
  int b = blockIdx.x / 5, cb = blockIdx.x % 5;
  int tid = threadIdx.x;
  int c = cb * 256 + tid;
  __shared__ float h1s[DD], fns[DD];
  if (tid < DD) { h1s[tid] = h1[(size_t)b * DD + tid]; fns[tid] = fnorm[(size_t)b * DD + tid]; }
  __syncthreads();
  if (c < NLOC) {
    float a1 = pr_b2[c], a2 = 0.0f;
    for (int k = 0; k < DD; k++) {
      a1 += h1s[k] * pr_w2[(size_t)k * NLOC + c];
      a2 += fns[k] * pnormT[(size_t)k * NLOC + c];
    }
    float tt = fminf(fmaxf(temp[0], 0.5f), 3.0f);
    out[(size_t)b * NLOC + c] = (0.5f * a1 + 7.5f * a2) / tt;
  }
}

// ---------------------------------------------------------------------------
extern "C" void kernel_launch(void* const* d_in, const int* in_sizes, int n_in,
                              void* d_out, int out_size, void* d_ws, size_t ws_size,
                              hipStream_t stream) {
  const int* loc_seq   = (const int*)d_in[0];
  const int* user_seq  = (const int*)d_in[1];
  const int* wk_seq    = (const int*)d_in[2];
  const int* sm_seq    = (const int*)d_in[3];
  const int* dur_seq   = (const int*)d_in[4];
  const int* diff_seq  = (const int*)d_in[5];
  const int* seq_len   = (const int*)d_in[6];
  const float* loc_table = (const float*)d_in[7];
  const float* user_table= (const float*)d_in[8];
  const float* wk_table  = (const float*)d_in[9];
  const float* hr_table  = (const float*)d_in[10];
  const float* in_w   = (const float*)d_in[11];
  const float* in_b   = (const float*)d_in[12];
  const float* in_g   = (const float*)d_in[13];
  const float* in_be  = (const float*)d_in[14];
  const float* pos_emb= (const float*)d_in[15];
  const float* qkv_w  = (const float*)d_in[16];
  const float* proj_w = (const float*)d_in[17];
  const float* proj_b = (const float*)d_in[18];
  const float* rel_emb= (const float*)d_in[19];
  const float* n1_g   = (const float*)d_in[20];
  const float* n1_b   = (const float*)d_in[21];
  const float* ffn_w1 = (const float*)d_in[22];
  const float* ffn_b1 = (const float*)d_in[23];
  const float* ffn_w2 = (const float*)d_in[24];
  const float* ffn_b2 = (const float*)d_in[25];
  const float* n2_g   = (const float*)d_in[26];
  const float* n2_b   = (const float*)d_in[27];
  const float* fn_g   = (const float*)d_in[28];
  const float* fn_b   = (const float*)d_in[29];
  const float* pr_w1  = (const float*)d_in[30];
  const float* pr_b1  = (const float*)d_in[31];
  const float* pr_w2  = (const float*)d_in[32];
  const float* pr_b2  = (const float*)d_in[33];
  const float* protos = (const float*)d_in[34];
  const float* temp   = (const float*)d_in[35];
  float* out = (float*)d_out;

  float* x      = (float*)d_ws;
  float* o      = x + (size_t)BB * LL * DD;
  float* wT     = o + (size_t)BB * LL * DD;          // 61440 floats
  float* fnorm  = wT + 61440;
  float* h1     = fnorm + (size_t)BB * DD;
  float* pnormT = h1 + (size_t)BB * DD;

  k_wprep<<<240, 256, 0, stream>>>(qkv_w, wT);

  k_embed<<<BB * LL / 48, 256, 0, stream>>>(loc_seq, user_seq, wk_seq, sm_seq,
                                            dur_seq, diff_seq, loc_table,
                                            user_table, wk_table, hr_table,
                                            in_w, in_b, in_g, in_be, pos_emb, x);

  for (int l = 0; l < NLNUM; l++) {
    k_battn<<<BB, 256, 0, stream>>>(x, loc_seq, wT + (size_t)l * 20480,
                                    rel_emb + (size_t)l * RELN * HDD, o);
    k_proj_ln<<<BB * LL / 48, 256, 0, stream>>>(o, proj_w + (size_t)l * DD * DD,
                                                proj_b + (size_t)l * DD,
                                                n1_g + (size_t)l * DD,
                                                n1_b + (size_t)l * DD, x);
    k_ffn<<<BB * LL / 48, 256, 0, stream>>>(ffn_w1 + (size_t)l * DD * DFF,
                                            ffn_b1 + (size_t)l * DFF,
                                            ffn_w2 + (size_t)l * DFF * DD,
                                            ffn_b2 + (size_t)l * DD,
                                            n2_g + (size_t)l * DD,
                                            n2_b + (size_t)l * DD, x);
  }

  k_pnorm<<<NLOC, 128, 0, stream>>>(protos, pnormT);
  k_final<<<BB, 128, 0, stream>>>(x, seq_len, fn_g, fn_b, pr_w1, pr_b1, fnorm, h1);
  k_logits<<<BB * 5, 256, 0, stream>>>(h1, fnorm, pr_w2, pr_b2, pnormT, temp, out);
}

// Round 11
// 1645.946 us; speedup vs baseline: 1.2217x; 1.2217x over previous
//
#include <hip/hip_runtime.h>
#include <hip/hip_bf16.h>
#include <math.h>

#define BB   2048
#define LL   60
#define DD   80
#define HH   8
#define HDD  10
#define NLNUM 3
#define NLOC 1187
#define DFF  160
#define IN_DIM 138
#define RELN 119
#define SCS  68   // sc row stride (floats): 68 mod 32 = 4 -> rows spread banks
#define XP   21   // padded tile row stride in float4 (84 words, !=0 mod 32)
#define HP   41   // padded h-tile row stride in float4 (164 words)
#define VP   35   // vin row stride in float4 (140 words)

// Branchless gelu: erf via Abramowitz-Stegun 7.1.26 (|err| <= 1.5e-7).
// Avoids libm erff whose branchy inline blew k_ffn1 to 256 VGPRs + spill.
__device__ __forceinline__ float gelu_f(float a) {
  float x = fabsf(a) * 0.70710678118654752f;
  float t = 1.0f / (1.0f + 0.3275911f * x);
  float y = t * (0.254829592f + t * (-0.284496736f + t * (1.421413741f +
            t * (-1.453152027f + t * 1.061405429f))));
  float e = 1.0f - y * __expf(-x * x);           // erf(|x|)
  float erf_s = copysignf(e, a);
  return 0.5f * a * (1.0f + erf_s);
}

// ---------------------------------------------------------------------------
// K1: embed+inproj+LN as a 48-token GEMM block
// ---------------------------------------------------------------------------
__global__ __launch_bounds__(256) void k_embed(
    const int* __restrict__ loc_seq, const int* __restrict__ user_seq,
    const int* __restrict__ wk_seq, const int* __restrict__ sm_seq,
    const int* __restrict__ dur_seq, const int* __restrict__ diff_seq,
    const float* __restrict__ loc_table, const float* __restrict__ user_table,
    const float* __restrict__ wk_table, const float* __restrict__ hr_table,
    const float* __restrict__ in_w, const float* __restrict__ in_b,
    const float* __restrict__ in_g, const float* __restrict__ in_be,
    const float* __restrict__ pos_emb, float* __restrict__ x) {
  int tok0 = blockIdx.x * 48, tid = threadIdx.x;
  __shared__ __align__(16) float vin[48 * VP * 4];
  __shared__ __align__(16) float ws[140 * 80];
  __shared__ float mstd[96];

  float4* vin4 = (float4*)vin;
  float4* ws4  = (float4*)ws;

  for (int i = tid; i < 140 * 20; i += 256) {
    int r = i / 20, c = i % 20;
    float4 v = make_float4(0.0f, 0.0f, 0.0f, 0.0f);
    if (r < IN_DIM) v = *(const float4*)(in_w + r * 80 + c * 4);
    ws4[i] = v;
  }
  for (int i = tid; i < 48 * 35; i += 256) {
    int t = i / 35, s = i % 35;
    int tok = tok0 + t;
    float4 v;
    if (s < 20) {
      int loc = loc_seq[tok];
      v = *(const float4*)(loc_table + (size_t)loc * 80 + s * 4);
    } else if (s < 26) {
      int usr = user_seq[(tok / LL) * LL];
      v = *(const float4*)(user_table + usr * 24 + (s - 20) * 4);
    } else if (s < 30) {
      int wk = wk_seq[tok];
      v = *(const float4*)(wk_table + wk * 16 + (s - 26) * 4);
    } else if (s < 34) {
      int hr = sm_seq[tok] / 60; hr = min(max(hr, 0), 23);
      v = *(const float4*)(hr_table + hr * 16 + (s - 30) * 4);
    } else {
      v.x = (float)diff_seq[tok] / 10.0f;
      v.y = (float)dur_seq[tok] / 300.0f;
      v.z = 0.0f; v.w = 0.0f;
    }
    vin4[t * VP + s] = v;
  }
  __syncthreads();

  int tg = tid / 20, cg = tid % 20, t0 = tg * 4;
  float acc[4][4] = {};
  if (tid < 240) {
    #pragma unroll 7
    for (int iq = 0; iq < 35; iq++) {
      float4 xv[4], wv[4];
      #pragma unroll
      for (int dt = 0; dt < 4; dt++) xv[dt] = vin4[(t0 + dt) * VP + iq];
      #pragma unroll
      for (int di = 0; di < 4; di++) wv[di] = ws4[(iq * 4 + di) * 20 + cg];
      #pragma unroll
      for (int dt = 0; dt < 4; dt++) {
        const float* xp = (const float*)&xv[dt];
        #pragma unroll
        for (int di = 0; di < 4; di++) {
          const float* wp = (const float*)&wv[di];
          #pragma unroll
          for (int dc = 0; dc < 4; dc++) acc[dt][dc] += xp[di] * wp[dc];
        }
      }
    }
  }
  __syncthreads();
  if (tid < 240) {
    float4 bb = *(const float4*)(in_b + cg * 4);
    const float* bp = (const float*)&bb;
    #pragma unroll
    for (int dt = 0; dt < 4; dt++) {
      float4 y;
      y.x = acc[dt][0] + bp[0];
      y.y = acc[dt][1] + bp[1];
      y.z = acc[dt][2] + bp[2];
      y.w = acc[dt][3] + bp[3];
      vin4[(t0 + dt) * VP + cg] = y;
    }
  }
  __syncthreads();
  if (tid < 48) {
    float s = 0.0f, s2 = 0.0f;
    #pragma unroll
    for (int iq = 0; iq < 20; iq++) {
      float4 v = vin4[tid * VP + iq];
      s  += v.x + v.y + v.z + v.w;
      s2 += v.x * v.x + v.y * v.y + v.z * v.z + v.w * v.w;
    }
    float mean = s / 80.0f;
    float var  = fmaxf(s2 / 80.0f - mean * mean, 0.0f);
    mstd[tid] = mean; mstd[48 + tid] = rsqrtf(var + 1e-5f);
  }
  __syncthreads();
  for (int e = tid; e < 960; e += 256) {
    int t = e / 20, c4 = e % 20;
    float4 v = vin4[t * VP + c4];
    float4 gg = *(const float4*)(in_g + c4 * 4);
    float4 bb = *(const float4*)(in_be + c4 * 4);
    float4 pe = *(const float4*)(pos_emb + ((tok0 + t) % LL) * 80 + c4 * 4);
    float m = mstd[t], r = mstd[48 + t];
    float4 out;
    out.x = (v.x - m) * r * gg.x + bb.x + pe.x;
    out.y = (v.y - m) * r * gg.y + bb.y + pe.y;
    out.z = (v.z - m) * r * gg.z + bb.z + pe.z;
    out.w = (v.w - m) * r * gg.w + bb.w + pe.w;
    ((float4*)(x + (size_t)tok0 * 80))[e] = out;
  }
}

// ---------------------------------------------------------------------------
// K2a: qkv GEMM per batch row b: [60 x 80] @ [80 x 240] -> qkvo[b][c][t]
// ---------------------------------------------------------------------------
__global__ __launch_bounds__(256) void k_qkv(
    const float* __restrict__ x, const float* __restrict__ qkv_w,
    float* __restrict__ qkvo) {
  int b = blockIdx.x, tid = threadIdx.x;
  __shared__ __align__(16) float xs[LL * XP * 4];
  __shared__ __align__(16) float ws[DD * DD];

  const float4* xb4 = (const float4*)(x + (size_t)b * LL * DD);
  float4* xs4 = (float4*)xs;
  for (int i = tid; i < LL * 20; i += 256) xs4[(i / 20) * XP + (i % 20)] = xb4[i];
  float4* ws4 = (float4*)ws;

  for (int c0 = 0; c0 < 240; c0 += 80) {
    __syncthreads();
    for (int i = tid; i < 80 * 20; i += 256)
      ws4[i] = *(const float4*)(qkv_w + (i / 20) * 240 + c0 + (i % 20) * 4);
    __syncthreads();
    for (int slot = tid; slot < 300; slot += 256) {
      int tg = slot / 20, cg = slot % 20;
      int t0 = tg * 4;
      float acc[4][4] = {};
      #pragma unroll
      for (int iq = 0; iq < 20; iq++) {
        float4 xv[4], wv[4];
        #pragma unroll
        for (int dt = 0; dt < 4; dt++) xv[dt] = xs4[(t0 + dt) * XP + iq];
        #pragma unroll
        for (int di = 0; di < 4; di++) wv[di] = ws4[(iq * 4 + di) * 20 + cg];
        #pragma unroll
        for (int dt = 0; dt < 4; dt++) {
          const float* xp = (const float*)&xv[dt];
          #pragma unroll
          for (int di = 0; di < 4; di++) {
            const float* wp = (const float*)&wv[di];
            #pragma unroll
            for (int dc = 0; dc < 4; dc++) acc[dt][dc] += xp[di] * wp[dc];
          }
        }
      }
      float* qb = qkvo + (size_t)b * 14400 + (size_t)(c0 + cg * 4) * 60 + t0;
      #pragma unroll
      for (int dc = 0; dc < 4; dc++)
        *(float4*)(qb + dc * 60) = make_float4(acc[0][dc], acc[1][dc], acc[2][dc], acc[3][dc]);
    }
  }
}

// ---------------------------------------------------------------------------
// K2b: attention per (b,h), 256 threads. Per-thread-row softmax.
// ---------------------------------------------------------------------------
__global__ __launch_bounds__(256) void k_attn(
    const float* __restrict__ qkvo, const int* __restrict__ loc_seq,
    const float* __restrict__ rel_emb,
    float* __restrict__ o) {
  int bh = blockIdx.x;
  int b = bh >> 3, h = bh & 7;
  int tid = threadIdx.x;

  __shared__ __align__(16) float qs[HDD * 60];
  __shared__ __align__(16) float ks[HDD * 60];
  __shared__ __align__(16) float vs[HDD * 60];
  __shared__ __align__(16) float relT[HDD * 120];
  __shared__ __align__(16) float sc[60 * SCS];
  __shared__ __align__(16) float rsum[64];
  __shared__ float msk[60];

  const float4* src = (const float4*)(qkvo + (size_t)b * 14400);
  float4* q4 = (float4*)qs; float4* k4 = (float4*)ks; float4* v4 = (float4*)vs;
  for (int i = tid; i < 150; i += 256) {
    q4[i] = src[h * 150 + i];
    k4[i] = src[1200 + h * 150 + i];
    v4[i] = src[2400 + h * 150 + i];
  }
  for (int i = tid; i < RELN * HDD; i += 256) {
    int d = i / RELN, p = i % RELN;
    relT[d * 120 + p] = rel_emb[p * 10 + d];
  }
  if (tid < 60) msk[tid] = (loc_seq[b * LL + tid] == 0) ? 1.0f : 0.0f;
  __syncthreads();

  if (tid < 225) {
    int ig = tid / 15, jg = tid % 15;
    int i0 = ig * 4, j0 = jg * 4;
    int w0 = j0 - i0 + 56;
    float acc[4][4] = {};
    #pragma unroll
    for (int d = 0; d < 10; d++) {
      float4 qv = *(const float4*)(qs + d * 60 + i0);
      float4 kv = *(const float4*)(ks + d * 60 + j0);
      float4 rA = *(const float4*)(relT + d * 120 + w0);
      float4 rB = *(const float4*)(relT + d * 120 + w0 + 4);
      float rr[8] = {rA.x, rA.y, rA.z, rA.w, rB.x, rB.y, rB.z, rB.w};
      const float* qp = (const float*)&qv;
      const float* kp = (const float*)&kv;
      #pragma unroll
      for (int di = 0; di < 4; di++)
        #pragma unroll
        for (int dj = 0; dj < 4; dj++)
          acc[di][dj] += qp[di] * (kp[dj] + rr[dj - di + 3]);
    }
    const float scale = 0.31622776601683794f;
    #pragma unroll
    for (int di = 0; di < 4; di++) {
      #pragma unroll
      for (int dj = 0; dj < 4; dj++) {
        float v = acc[di][dj] * scale;
        if (msk[j0 + dj] != 0.0f) v = -1e30f;
        acc[di][dj] = v;
      }
      *(float4*)(sc + (i0 + di) * SCS + j0) =
          make_float4(acc[di][0], acc[di][1], acc[di][2], acc[di][3]);
    }
  }
  __syncthreads();

  if (tid < 60) {
    float* row = sc + tid * SCS;
    int c = (tid >> 3) & 7;
    float m0 = -3.0e38f, m1 = -3.0e38f, m2 = -3.0e38f, m3 = -3.0e38f;
    #pragma unroll
    for (int s = 0; s < 15; s++) {
      int k = c + s; if (k >= 15) k -= 15;
      float4 v = *(const float4*)(row + 4 * k);
      m0 = fmaxf(m0, v.x); m1 = fmaxf(m1, v.y);
      m2 = fmaxf(m2, v.z); m3 = fmaxf(m3, v.w);
    }
    float m = fmaxf(fmaxf(m0, m1), fmaxf(m2, m3));
    float s0 = 0.0f, s1 = 0.0f, s2 = 0.0f, s3 = 0.0f;
    #pragma unroll
    for (int s = 0; s < 15; s++) {
      int k = c + s; if (k >= 15) k -= 15;
      float4 v = *(float4*)(row + 4 * k);
      v.x = __expf(v.x - m); v.y = __expf(v.y - m);
      v.z = __expf(v.z - m); v.w = __expf(v.w - m);
      *(float4*)(row + 4 * k) = v;
      s0 += v.x; s1 += v.y; s2 += v.z; s3 += v.w;
    }
    rsum[tid] = 1.0f / (s0 + s1 + s2 + s3);
  }
  __syncthreads();

  if (tid < 150) {
    int ig = tid / 10, d = tid % 10;
    float acc[4] = {0, 0, 0, 0};
    #pragma unroll 5
    for (int jq = 0; jq < 15; jq++) {
      float4 vv = *(const float4*)(vs + d * 60 + jq * 4);
      #pragma unroll
      for (int di = 0; di < 4; di++) {
        float4 av = *(const float4*)(sc + (ig + 15 * di) * SCS + jq * 4);
        acc[di] += av.x * vv.x + av.y * vv.y + av.z * vv.z + av.w * vv.w;
      }
    }
    #pragma unroll
    for (int di = 0; di < 4; di++) {
      float r = rsum[ig + 15 * di];
      o[((size_t)b * 60 + ig + 15 * di) * 80 + h * 10 + d] = acc[di] * r;
    }
  }
}

// ---------------------------------------------------------------------------
// K3: x = LN(x + o @ proj_w + proj_b)  — 48 tokens/block
// ---------------------------------------------------------------------------
__global__ __launch_bounds__(256) void k_proj_ln(
    const float* __restrict__ o, const float* __restrict__ proj_w,
    const float* __restrict__ proj_b, const float* __restrict__ g,
    const float* __restrict__ be, float* __restrict__ x) {
  int tok0 = blockIdx.x * 48, tid = threadIdx.x;
  __shared__ __align__(16) float os[48 * XP * 4];
  __shared__ __align__(16) float ws[80 * 80];
  __shared__ float mstd[96];

  float4* os4 = (float4*)os;
  const float4* ob4 = (const float4*)(o + (size_t)tok0 * 80);
  for (int i = tid; i < 960; i += 256) os4[(i / 20) * XP + (i % 20)] = ob4[i];
  float4* ws4 = (float4*)ws;
  for (int i = tid; i < 1600; i += 256)
    ws4[i] = *(const float4*)(proj_w + (i / 20) * 80 + (i % 20) * 4);
  __syncthreads();

  int tg = tid / 20, cg = tid % 20, t0 = tg * 4;
  float acc[4][4] = {};
  if (tid < 240) {
    #pragma unroll
    for (int iq = 0; iq < 20; iq++) {
      float4 xv[4], wv[4];
      #pragma unroll
      for (int dt = 0; dt < 4; dt++) xv[dt] = os4[(t0 + dt) * XP + iq];
      #pragma unroll
      for (int di = 0; di < 4; di++) wv[di] = ws4[(iq * 4 + di) * 20 + cg];
      #pragma unroll
      for (int dt = 0; dt < 4; dt++) {
        const float* xp = (const float*)&xv[dt];
        #pragma unroll
        for (int di = 0; di < 4; di++) {
          const float* wp = (const float*)&wv[di];
          #pragma unroll
          for (int dc = 0; dc < 4; dc++) acc[dt][dc] += xp[di] * wp[dc];
        }
      }
    }
  }
  __syncthreads();
  if (tid < 240) {
    float4 pb = *(const float4*)(proj_b + cg * 4);
    const float* pbp = (const float*)&pb;
    #pragma unroll
    for (int dt = 0; dt < 4; dt++) {
      float4 xr = *(const float4*)(x + (size_t)(tok0 + t0 + dt) * 80 + cg * 4);
      const float* xrp = (const float*)&xr;
      float4 out;
      out.x = acc[dt][0] + pbp[0] + xrp[0];
      out.y = acc[dt][1] + pbp[1] + xrp[1];
      out.z = acc[dt][2] + pbp[2] + xrp[2];
      out.w = acc[dt][3] + pbp[3] + xrp[3];
      os4[(t0 + dt) * XP + cg] = out;
    }
  }
  __syncthreads();
  if (tid < 48) {
    float s = 0.0f, s2 = 0.0f;
    #pragma unroll
    for (int iq = 0; iq < 20; iq++) {
      float4 v = os4[tid * XP + iq];
      s  += v.x + v.y + v.z + v.w;
      s2 += v.x * v.x + v.y * v.y + v.z * v.z + v.w * v.w;
    }
    float mean = s / 80.0f;
    float var  = fmaxf(s2 / 80.0f - mean * mean, 0.0f);
    mstd[tid] = mean; mstd[48 + tid] = rsqrtf(var + 1e-5f);
  }
  __syncthreads();
  for (int e = tid; e < 960; e += 256) {
    int t = e / 20, c4 = e % 20;
    float4 v = os4[t * XP + c4];
    float4 gg = *(const float4*)(g + c4 * 4);
    float4 bb = *(const float4*)(be + c4 * 4);
    float m = mstd[t], r = mstd[48 + t];
    float4 out;
    out.x = (v.x - m) * r * gg.x + bb.x;
    out.y = (v.y - m) * r * gg.y + bb.y;
    out.z = (v.z - m) * r * gg.z + bb.z;
    out.w = (v.w - m) * r * gg.w + bb.w;
    ((float4*)(x + (size_t)tok0 * 80))[e] = out;
  }
}

// ---------------------------------------------------------------------------
// K4: fused FFN: x = LN(x + W2ᵀgelu(W1ᵀx + b1) + b2)  — 48 tokens/block
// ---------------------------------------------------------------------------
__global__ __launch_bounds__(256) void k_ffn(
    const float* __restrict__ w1, const float* __restrict__ b1,
    const float* __restrict__ w2, const float* __restrict__ b2,
    const float* __restrict__ g, const float* __restrict__ be,
    float* __restrict__ x) {
  int tok0 = blockIdx.x * 48, tid = threadIdx.x;
  __shared__ __align__(16) float xs[48 * XP * 4];
  __shared__ __align__(16) float hs[48 * HP * 4];
  __shared__ __align__(16) float ws[80 * 80];
  __shared__ float mstd[96];

  float4* xs4 = (float4*)xs;
  float4* hs4 = (float4*)hs;
  float4* ws4 = (float4*)ws;
  const float4* xb4 = (const float4*)(x + (size_t)tok0 * 80);
  for (int i = tid; i < 960; i += 256) xs4[(i / 20) * XP + (i % 20)] = xb4[i];

  int tg = tid / 20, cg = tid % 20, t0 = tg * 4;

  for (int c0 = 0; c0 < 160; c0 += 80) {
    __syncthreads();
    for (int i = tid; i < 1600; i += 256)
      ws4[i] = *(const float4*)(w1 + (i / 20) * 160 + c0 + (i % 20) * 4);
    __syncthreads();
    if (tid < 240) {
      float acc[4][4] = {};
      #pragma unroll
      for (int iq = 0; iq < 20; iq++) {
        float4 xv[4], wv[4];
        #pragma unroll
        for (int dt = 0; dt < 4; dt++) xv[dt] = xs4[(t0 + dt) * XP + iq];
        #pragma unroll
        for (int di = 0; di < 4; di++) wv[di] = ws4[(iq * 4 + di) * 20 + cg];
        #pragma unroll
        for (int dt = 0; dt < 4; dt++) {
          const float* xp = (const float*)&xv[dt];
          #pragma unroll
          for (int di = 0; di < 4; di++) {
            const float* wp = (const float*)&wv[di];
            #pragma unroll
            for (int dc = 0; dc < 4; dc++) acc[dt][dc] += xp[di] * wp[dc];
          }
        }
      }
      float4 bb = *(const float4*)(b1 + c0 + cg * 4);
      const float* bp = (const float*)&bb;
      #pragma unroll
      for (int dt = 0; dt < 4; dt++) {
        float4 out;
        float* op = (float*)&out;
        #pragma unroll
        for (int dc = 0; dc < 4; dc++)
          op[dc] = gelu_f(acc[dt][dc] + bp[dc]);
        hs4[(t0 + dt) * HP + c0 / 4 + cg] = out;
      }
    }
  }

  float acc[4][4] = {};
  for (int k0 = 0; k0 < 160; k0 += 80) {
    __syncthreads();
    for (int i = tid; i < 1600; i += 256)
      ws4[i] = *(const float4*)(w2 + (size_t)(k0 + i / 20) * 80 + (i % 20) * 4);
    __syncthreads();
    if (tid < 240) {
      #pragma unroll
      for (int iq = 0; iq < 20; iq++) {
        float4 hv[4], wv[4];
        #pragma unroll
        for (int dt = 0; dt < 4; dt++) hv[dt] = hs4[(t0 + dt) * HP + k0 / 4 + iq];
        #pragma unroll
        for (int di = 0; di < 4; di++) wv[di] = ws4[(iq * 4 + di) * 20 + cg];
        #pragma unroll
        for (int dt = 0; dt < 4; dt++) {
          const float* hp = (const float*)&hv[dt];
          #pragma unroll
          for (int di = 0; di < 4; di++) {
            const float* wp = (const float*)&wv[di];
            #pragma unroll
            for (int dc = 0; dc < 4; dc++) acc[dt][dc] += hp[di] * wp[dc];
          }
        }
      }
    }
  }
  __syncthreads();
  if (tid < 240) {
    float4 bb = *(const float4*)(b2 + cg * 4);
    const float* bp = (const float*)&bb;
    #pragma unroll
    for (int dt = 0; dt < 4; dt++) {
      float4 xr = xs4[(t0 + dt) * XP + cg];
      const float* xrp = (const float*)&xr;
      float4 out;
      out.x = acc[dt][0] + bp[0] + xrp[0];
      out.y = acc[dt][1] + bp[1] + xrp[1];
      out.z = acc[dt][2] + bp[2] + xrp[2];
      out.w = acc[dt][3] + bp[3] + xrp[3];
      hs4[(t0 + dt) * HP + cg] = out;
    }
  }
  __syncthreads();
  if (tid < 48) {
    float s = 0.0f, s2 = 0.0f;
    #pragma unroll
    for (int iq = 0; iq < 20; iq++) {
      float4 v = hs4[tid * HP + iq];
      s  += v.x + v.y + v.z + v.w;
      s2 += v.x * v.x + v.y * v.y + v.z * v.z + v.w * v.w;
    }
    float mean = s / 80.0f;
    float var  = fmaxf(s2 / 80.0f - mean * mean, 0.0f);
    mstd[tid] = mean; mstd[48 + tid] = rsqrtf(var + 1e-5f);
  }
  __syncthreads();
  for (int e = tid; e < 960; e += 256) {
    int t = e / 20, c4 = e % 20;
    float4 v = hs4[t * HP + c4];
    float4 gg = *(const float4*)(g + c4 * 4);
    float4 bb = *(const float4*)(be + c4 * 4);
    float m = mstd[t], r = mstd[48 + t];
    float4 out;
    out.x = (v.x - m) * r * gg.x + bb.x;
    out.y = (v.y - m) * r * gg.y + bb.y;
    out.z = (v.z - m) * r * gg.z + bb.z;
    out.w = (v.w - m) * r * gg.w + bb.w;
    ((float4*)(x + (size_t)tok0 * 80))[e] = out;
  }
}

// ---------------------------------------------------------------------------
// K5: final LN at gathered position + fnorm + h1 = gelu(final@pr_w1+pr_b1)
// ---------------------------------------------------------------------------
__global__ __launch_bounds__(128) void k_final(
    const float* __restrict__ x, const int* __restrict__ seq_len,
    const float* __restrict__ fn_g, const float* __restrict__ fn_b,
    const float* __restrict__ pr_w1, const float* __restrict__ pr_b1,
    float* __restrict__ fnorm, float* __restrict__ h1) {
  int b = blockIdx.x, tid = threadIdx.x;
  __shared__ float red[128], red2[128];
  __shared__ float fbuf[DD];
  int t = seq_len[b] - 1; t = min(max(t, 0), LL - 1);
  float v = 0.0f;
  if (tid < DD) v = x[((size_t)b * LL + t) * DD + tid];
  red[tid]  = (tid < DD) ? v : 0.0f;
  red2[tid] = (tid < DD) ? v * v : 0.0f;
  __syncthreads();
  for (int s = 64; s > 0; s >>= 1) {
    if (tid < s) { red[tid] += red[tid + s]; red2[tid] += red2[tid + s]; }
    __syncthreads();
  }
  float mean = red[0] / DD;
  float var  = fmaxf(red2[0] / DD - mean * mean, 0.0f);
  float rstd = rsqrtf(var + 1e-5f);
  float f = 0.0f;
  if (tid < DD) { f = (v - mean) * rstd * fn_g[tid] + fn_b[tid]; fbuf[tid] = f; }
  __syncthreads();
  red[tid] = (tid < DD) ? f * f : 0.0f;
  __syncthreads();
  for (int s = 64; s > 0; s >>= 1) {
    if (tid < s) red[tid] += red[tid + s];
    __syncthreads();
  }
  float rn = 1.0f / fmaxf(sqrtf(red[0]), 1e-12f);
  if (tid < DD) {
    fnorm[(size_t)b * DD + tid] = f * rn;
    float gacc = pr_b1[tid];
    for (int i = 0; i < DD; i++) gacc += fbuf[i] * pr_w1[i * DD + tid];
    h1[(size_t)b * DD + tid] = gelu_f(gacc);
  }
}

// ---------------------------------------------------------------------------
// K6: normalize proto rows -> transposed pnormT[k][c]
// ---------------------------------------------------------------------------
__global__ __launch_bounds__(128) void k_pnorm(
    const float* __restrict__ protos, float* __restrict__ pnormT) {
  int c = blockIdx.x, tid = threadIdx.x;
  __shared__ float red[128];
  float v = 0.0f;
  if (tid < DD) v = protos[(size_t)c * DD + tid];
  red[tid] = (tid < DD) ? v * v : 0.0f;
  __syncthreads();
  for (int s = 64; s > 0; s >>= 1) {
    if (tid < s) red[tid] += red[tid + s];
    __syncthreads();
  }
  float rn = 1.0f / fmaxf(sqrtf(red[0]), 1e-12f);
  if (tid < DD) pnormT[(size_t)tid * NLOC + c] = v * rn;
}

// ---------------------------------------------------------------------------
// K7: logits — 4 batch rows per block; each pr_w2/pnormT column read serves
// 4 outputs (L2/L3 traffic ~1.5 GB -> ~0.39 GB per dispatch).
// ---------------------------------------------------------------------------
__global__ __launch_bounds__(256) void k_logits(
    const float* __restrict__ h1, const float* __restrict__ fnorm,
    const float* __restrict__ pr_w2, const float* __restrict__ pr_b2,
    const float* __restrict__ pnormT, const float* __restrict__ temp,
    float* __restrict__ out) {
  int b0 = (blockIdx.x / 5) * 4, cb = blockIdx.x % 5;
  int tid = threadIdx.x;
  int c = cb * 256 + tid;
  __shared__ float h1s[4][DD], fns[4][DD];
  for (int i = tid; i < 4 * DD; i += 256) {
    int j = i / DD, k = i % DD;
    h1s[j][k] = h1[(size_t)(b0 + j) * DD + k];
    fns[j][k] = fnorm[(size_t)(b0 + j) * DD + k];
  }
  __syncthreads();
  if (c < NLOC) {
    float a1[4] = {0, 0, 0, 0}, a2[4] = {0, 0, 0, 0};
    for (int k = 0; k < DD; k++) {
      float w = pr_w2[(size_t)k * NLOC + c];
      float p = pnormT[(size_t)k * NLOC + c];
      #pragma unroll
      for (int j = 0; j < 4; j++) {
        a1[j] += h1s[j][k] * w;
        a2[j] += fns[j][k] * p;
      }
    }
    float pb = pr_b2[c];
    float tt = fminf(fmaxf(temp[0], 0.5f), 3.0f);
    #pragma unroll
    for (int j = 0; j < 4; j++)
      out[(size_t)(b0 + j) * NLOC + c] = (0.5f * (a1[j] + pb) + 7.5f * a2[j]) / tt;
  }
}

// ---------------------------------------------------------------------------
extern "C" void kernel_launch(void* const* d_in, const int* in_sizes, int n_in,
                              void* d_out, int out_size, void* d_ws, size_t ws_size,
                              hipStream_t stream) {
  const int* loc_seq   = (const int*)d_in[0];
  const int* user_seq  = (const int*)d_in[1];
  const int* wk_seq    = (const int*)d_in[2];
  const int* sm_seq    = (const int*)d_in[3];
  const int* dur_seq   = (const int*)d_in[4];
  const int* diff_seq  = (const int*)d_in[5];
  const int* seq_len   = (const int*)d_in[6];
  const float* loc_table = (const float*)d_in[7];
  const float* user_table= (const float*)d_in[8];
  const float* wk_table  = (const float*)d_in[9];
  const float* hr_table  = (const float*)d_in[10];
  const float* in_w   = (const float*)d_in[11];
  const float* in_b   = (const float*)d_in[12];
  const float* in_g   = (const float*)d_in[13];
  const float* in_be  = (const float*)d_in[14];
  const float* pos_emb= (const float*)d_in[15];
  const float* qkv_w  = (const float*)d_in[16];
  const float* proj_w = (const float*)d_in[17];
  const float* proj_b = (const float*)d_in[18];
  const float* rel_emb= (const float*)d_in[19];
  const float* n1_g   = (const float*)d_in[20];
  const float* n1_b   = (const float*)d_in[21];
  const float* ffn_w1 = (const float*)d_in[22];
  const float* ffn_b1 = (const float*)d_in[23];
  const float* ffn_w2 = (const float*)d_in[24];
  const float* ffn_b2 = (const float*)d_in[25];
  const float* n2_g   = (const float*)d_in[26];
  const float* n2_b   = (const float*)d_in[27];
  const float* fn_g   = (const float*)d_in[28];
  const float* fn_b   = (const float*)d_in[29];
  const float* pr_w1  = (const float*)d_in[30];
  const float* pr_b1  = (const float*)d_in[31];
  const float* pr_w2  = (const float*)d_in[32];
  const float* pr_b2  = (const float*)d_in[33];
  const float* protos = (const float*)d_in[34];
  const float* temp   = (const float*)d_in[35];
  float* out = (float*)d_out;

  float* x      = (float*)d_ws;
  float* o      = x + (size_t)BB * LL * DD;
  float* qkvo   = o + (size_t)BB * LL * DD;
  float* fnorm  = qkvo + (size_t)BB * 14400;
  float* h1     = fnorm + (size_t)BB * DD;
  float* pnormT = h1 + (size_t)BB * DD;

  k_embed<<<BB * LL / 48, 256, 0, stream>>>(loc_seq, user_seq, wk_seq, sm_seq,
                                            dur_seq, diff_seq, loc_table,
                                            user_table, wk_table, hr_table,
                                            in_w, in_b, in_g, in_be, pos_emb, x);

  for (int l = 0; l < NLNUM; l++) {
    k_qkv<<<BB, 256, 0, stream>>>(x, qkv_w + (size_t)l * 80 * 240, qkvo);
    k_attn<<<BB * HH, 256, 0, stream>>>(qkvo, loc_seq,
                                        rel_emb + (size_t)l * RELN * HDD, o);
    k_proj_ln<<<BB * LL / 48, 256, 0, stream>>>(o, proj_w + (size_t)l * DD * DD,
                                                proj_b + (size_t)l * DD,
                                                n1_g + (size_t)l * DD,
                                                n1_b + (size_t)l * DD, x);
    k_ffn<<<BB * LL / 48, 256, 0, stream>>>(ffn_w1 + (size_t)l * DD * DFF,
                                            ffn_b1 + (size_t)l * DFF,
                                            ffn_w2 + (size_t)l * DFF * DD,
                                            ffn_b2 + (size_t)l * DD,
                                            n2_g + (size_t)l * DD,
                                            n2_b + (size_t)l * DD, x);
  }

  k_pnorm<<<NLOC, 128, 0, stream>>>(protos, pnormT);
  k_final<<<BB, 128, 0, stream>>>(x, seq_len, fn_g, fn_b, pr_w1, pr_b1, fnorm, h1);
  k_logits<<<(BB / 4) * 5, 256, 0, stream>>>(h1, fnorm, pr_w2, pr_b2, pnormT, temp, out);
}